// Round 13
// baseline (12.285 us; speedup 1.0000x reference)
//
#include <hip/hip_runtime.h>

#define KAPPA 0.276f
#define NTRI 8256        // 128*129/2 packed floats per batch
#define BATCH 1024
#define SCALE (1.0f / (128.0f * 1024.0f))   // /trace2(=128), /B for mean

// dst lane i <- src lane (i+2)&15 within each 16-lane row: row_ror:14 (0x12E).
// Implements B-partner kB(k) = (k&0x70)|((k+2)&15) on register data; applying
// it to the diagonal-masked own value also inherits the partner's mask.
__device__ __forceinline__ float rotl2(float v) {
    return __int_as_float(__builtin_amdgcn_mov_dpp(__float_as_int(v),
                                                   0x12E, 0xF, 0xF, false));
}

__global__ __launch_bounds__(512) void trace_kernel(const float* __restrict__ net_out,
                                                    const float* __restrict__ U1,
                                                    float* __restrict__ ws) {
    const int bid = blockIdx.x;               // one block per batch
    // XCD-aware swizzle: XCD x (dispatch round-robins bid&7) owns contiguous
    // batches [128x, 128x+128) -> ~4.2 MB working set, ~L2-resident per XCD.
    const int xcd = bid & 7;
    const int b   = (xcd << 7) + (bid >> 3);
    const int tid = threadIdx.x;
    const int w   = tid >> 6;                 // wave 0..7 = row class r
    const int l   = tid & 63;                 // lane owns elements k=l, k=l+64 per row
    const int r   = w;                        // rows r, r+8, ..., r+120

    const float* __restrict__ X = net_out + (size_t)b * NTRI;
    const float* __restrict__ U = U1 + (size_t)b * 128;

    // per-lane coefficients (site of element k is k>>1); HW cos (rel err ~1e-5)
    const float m2k = -2.0f * KAPPA;
    const float cAl = m2k * __cosf(U[(l >> 1)]);
    const float cAh = m2k * __cosf(U[32 + (l >> 1)]);
    const float cBl = m2k * __cosf(U[64 + (l >> 1)]);
    const float cBh = m2k * __cosf(U[96 + (l >> 1)]);

    const int  sidx = (l + 16) & 63;          // A-partner source lane
    const bool lo48 = (l < 48);

    float sq = 0.f, hAl = 0.f, hBl = 0.f, hAh = 0.f, hBh = 0.f;

    // ---- rows i = r .. r+56 : only low half valid (k <= i < 64) ----
    {
        int i = r;
        int o = (r * (r + 1)) >> 1;
        #pragma unroll 4
        for (int t = 0; t < 8; ++t) {
            const float* __restrict__ R = X + o;
            float x = R[l];
            x = (l <= i) ? x : 0.f;
            // A-partner: x of lane l+16 (mask inherited); zero for l>=48 (k+16 > i < 64)
            float ash = __shfl(x, sidx, 64);
            float a   = lo48 ? ash : 0.f;
            float bb  = rotl2(x);             // B-partner value+mask via DPP
            sq  = fmaf(x, x,  sq);
            hAl = fmaf(x, a,  hAl);
            hBl = fmaf(x, bb, hBl);
            o += (i << 3) + 36;               // tri(i+8)-tri(i)
            i += 8;
        }
    }
    // ---- rows i = r+64 .. r+120 : both halves ----
    {
        int i = r + 64;
        int o = (i * (i + 1)) >> 1;
        #pragma unroll 4
        for (int t = 0; t < 8; ++t) {
            const float* __restrict__ R = X + o;
            float x  = R[l];                  // k=l <= 63 < i: always valid
            float xh = R[l + 64];
            xh = (l + 64 <= i) ? xh : 0.f;

            // A-partners via 16-lane rotation of the (x, xh) register pair;
            // masks inherited exactly:
            //   a(l)  = l<48 ? x(l+16)  : xh(l-48)   [k_A = l+16]
            //   ah(l) = l<48 ? xh(l+16) : x(l-48)    [k_A = (l+80)&127]
            float sx  = __shfl(x,  sidx, 64);
            float sxh = __shfl(xh, sidx, 64);
            float a   = lo48 ? sx  : sxh;
            float ah  = lo48 ? sxh : sx;

            float bb = rotl2(x);              // always valid (kbl <= 63 < i)
            float bh = rotl2(xh);             // mask inherited

            sq  = fmaf(x,  x,  sq);
            sq  = fmaf(xh, xh, sq);
            hAl = fmaf(x,  a,  hAl);
            hBl = fmaf(x,  bb, hBl);
            hAh = fmaf(xh, ah, hAh);
            hBh = fmaf(xh, bh, hBh);

            o += (i << 3) + 36;
            i += 8;
        }
    }

    float val = sq + cAl * hAl + cAh * hAh + cBl * hBl + cBh * hBh;

    // wave reduce
    #pragma unroll
    for (int off = 32; off > 0; off >>= 1)
        val += __shfl_down(val, off, 64);

    __shared__ float red[8];
    if (l == 0) red[w] = val;
    __syncthreads();
    if (tid == 0) {
        float p = 0.f;
        #pragma unroll
        for (int j = 0; j < 8; ++j) p += red[j];
        ws[bid] = p;
    }
}

__global__ __launch_bounds__(1024) void reduce_kernel(const float* __restrict__ ws,
                                                      float* __restrict__ out) {
    const int tid = threadIdx.x;
    float v = ws[tid];                        // 1 load/thread, wide issue
    #pragma unroll
    for (int off = 32; off > 0; off >>= 1)
        v += __shfl_down(v, off, 64);
    __shared__ float red[16];
    if ((tid & 63) == 0) red[tid >> 6] = v;
    __syncthreads();
    if (tid < 64) {
        float s = (tid < 16) ? red[tid] : 0.f;
        #pragma unroll
        for (int off = 8; off > 0; off >>= 1)
            s += __shfl_down(s, off, 64);
        if (tid == 0) out[0] = s * SCALE;
    }
}

extern "C" void kernel_launch(void* const* d_in, const int* in_sizes, int n_in,
                              void* d_out, int out_size, void* d_ws, size_t ws_size,
                              hipStream_t stream) {
    const float* net_out = (const float*)d_in[0];  // (1024, 8256) fp32
    const float* U1      = (const float*)d_in[1];  // (1024, 2, 8, 8) fp32
    float* out = (float*)d_out;                    // scalar fp32
    float* ws  = (float*)d_ws;                     // >= BATCH floats

    trace_kernel<<<BATCH, 512, 0, stream>>>(net_out, U1, ws);
    reduce_kernel<<<1, 1024, 0, stream>>>(ws, out);
}

// Round 14
// 11.745 us; speedup vs baseline: 1.0460x; 1.0460x over previous
//
#include <hip/hip_runtime.h>

#define KAPPA 0.276f
#define NTRI 8256        // 128*129/2 packed floats per batch
#define BATCH 1024
#define SCALE (1.0f / (128.0f * 1024.0f))   // /trace2(=128), /B for mean

// dst lane i <- src lane (i+2)&15 within each 16-lane row: row_ror:14 (0x12E).
// Implements B-partner kB(k) = (k&0x70)|((k+2)&15) on register data; applying
// it to the diagonal-masked own value also inherits the partner's mask.
__device__ __forceinline__ float rotl2(float v) {
    return __int_as_float(__builtin_amdgcn_mov_dpp(__float_as_int(v),
                                                   0x12E, 0xF, 0xF, false));
}

__global__ __launch_bounds__(512) void trace_kernel(const float* __restrict__ net_out,
                                                    const float* __restrict__ U1,
                                                    float* __restrict__ ws) {
    const int bid = blockIdx.x;               // one block per batch
    // XCD-aware swizzle: XCD x (dispatch round-robins bid&7) owns contiguous
    // batches [128x, 128x+128) for L2 locality.
    const int xcd = bid & 7;
    const int b   = (xcd << 7) + (bid >> 3);
    const int tid = threadIdx.x;
    const int w   = tid >> 6;                 // wave 0..7 = row class r
    const int l   = tid & 63;                 // lane owns elements k=l, k=l+64 per row
    const int r   = w;                        // rows r, r+8, ..., r+120

    const float* __restrict__ X = net_out + (size_t)b * NTRI;
    const float* __restrict__ U = U1 + (size_t)b * 128;

    // ---- phase 1: issue ALL 24 global loads (max MLP; cold-HBM latency overlap) ----
    float vlo[8], vx[8], vxh[8];
    {
        int i = r, o = (r * (r + 1)) >> 1;
        #pragma unroll
        for (int t = 0; t < 8; ++t) {
            vlo[t] = X[o + l];
            o += (i << 3) + 36;               // tri(i+8)-tri(i)
            i += 8;
        }
    }
    {
        int i = r + 64, o = ((r + 64) * (r + 65)) >> 1;
        #pragma unroll
        for (int t = 0; t < 8; ++t) {
            vx[t]  = X[o + l];
            vxh[t] = X[o + l + 64];
            o += (i << 3) + 36;
            i += 8;
        }
    }

    // per-lane coefficients (site of element k is k>>1); HW cos (rel err ~1e-5)
    const float m2k = -2.0f * KAPPA;
    const float cAl = m2k * __cosf(U[(l >> 1)]);
    const float cAh = m2k * __cosf(U[32 + (l >> 1)]);
    const float cBl = m2k * __cosf(U[64 + (l >> 1)]);
    const float cBh = m2k * __cosf(U[96 + (l >> 1)]);

    const int  sidx = (l + 16) & 63;          // A-partner source lane
    const bool lo48 = (l < 48);

    float sq = 0.f, hAl = 0.f, hBl = 0.f, hAh = 0.f, hBh = 0.f;

    // ---- phase 2: consume. Lane algebra identical to R12/R13 (absmax 0.0) ----
    #pragma unroll
    for (int t = 0; t < 8; ++t) {             // rows i = r .. r+56: low half only
        const int i = r + (t << 3);
        float x = vlo[t];
        x = (l <= i) ? x : 0.f;
        float ash = __shfl(x, sidx, 64);      // A-partner (mask inherited)
        float a   = lo48 ? ash : 0.f;         // k+16 > i for l>=48 here
        float bb  = rotl2(x);                 // B-partner via DPP
        sq  = fmaf(x, x,  sq);
        hAl = fmaf(x, a,  hAl);
        hBl = fmaf(x, bb, hBl);
    }
    #pragma unroll
    for (int t = 0; t < 8; ++t) {             // rows i = r+64 .. r+120: both halves
        const int i = r + 64 + (t << 3);
        float x  = vx[t];                     // k=l <= 63 < i: always valid
        float xh = vxh[t];
        xh = (l + 64 <= i) ? xh : 0.f;

        // A-partners via 16-lane rotation of (x, xh); masks inherited exactly:
        //   a(l)  = l<48 ? x(l+16)  : xh(l-48)   [k_A = l+16]
        //   ah(l) = l<48 ? xh(l+16) : x(l-48)    [k_A = (l+80)&127]
        float sx  = __shfl(x,  sidx, 64);
        float sxh = __shfl(xh, sidx, 64);
        float a   = lo48 ? sx  : sxh;
        float ah  = lo48 ? sxh : sx;

        float bb = rotl2(x);                  // always valid (kbl <= 63 < i)
        float bh = rotl2(xh);                 // mask inherited

        sq  = fmaf(x,  x,  sq);
        sq  = fmaf(xh, xh, sq);
        hAl = fmaf(x,  a,  hAl);
        hBl = fmaf(x,  bb, hBl);
        hAh = fmaf(xh, ah, hAh);
        hBh = fmaf(xh, bh, hBh);
    }

    float val = sq + cAl * hAl + cAh * hAh + cBl * hBl + cBh * hBh;

    // wave reduce
    #pragma unroll
    for (int off = 32; off > 0; off >>= 1)
        val += __shfl_down(val, off, 64);

    __shared__ float red[8];
    if (l == 0) red[w] = val;
    __syncthreads();
    if (tid == 0) {
        float p = 0.f;
        #pragma unroll
        for (int j = 0; j < 8; ++j) p += red[j];
        ws[bid] = p;
    }
}

__global__ __launch_bounds__(1024) void reduce_kernel(const float* __restrict__ ws,
                                                      float* __restrict__ out) {
    const int tid = threadIdx.x;
    float v = ws[tid];                        // 1 load/thread, wide issue
    #pragma unroll
    for (int off = 32; off > 0; off >>= 1)
        v += __shfl_down(v, off, 64);
    __shared__ float red[16];
    if ((tid & 63) == 0) red[tid >> 6] = v;
    __syncthreads();
    if (tid < 64) {
        float s = (tid < 16) ? red[tid] : 0.f;
        #pragma unroll
        for (int off = 8; off > 0; off >>= 1)
            s += __shfl_down(s, off, 64);
        if (tid == 0) out[0] = s * SCALE;
    }
}

extern "C" void kernel_launch(void* const* d_in, const int* in_sizes, int n_in,
                              void* d_out, int out_size, void* d_ws, size_t ws_size,
                              hipStream_t stream) {
    const float* net_out = (const float*)d_in[0];  // (1024, 8256) fp32
    const float* U1      = (const float*)d_in[1];  // (1024, 2, 8, 8) fp32
    float* out = (float*)d_out;                    // scalar fp32
    float* ws  = (float*)d_ws;                     // >= BATCH floats

    trace_kernel<<<BATCH, 512, 0, stream>>>(net_out, U1, ws);
    reduce_kernel<<<1, 1024, 0, stream>>>(ws, out);
}